// Round 6
// baseline (466.674 us; speedup 1.0000x reference)
//
#include <hip/hip_runtime.h>

// =====================================================================
// CNN encoder, fp32 world via fp16 MFMA (32x32x16, full-rate, R5).
// R6: s-plane ring pipeline. The conv slab's natural grain is one
// s-plane [2][320][8] = 10,240 B. Ring of 6 planes in LDS; phase p
// (114 total: 19 GEMM1 K-steps + 95 conv (kk,s) phases) consumes
// plane p while ds_writing plane p+5 from regs loaded at phase p-2.
// Staging is fully off the critical path; ONE barrier per phase;
// vmcnt discipline is implicit via register deps (reg-staging).
// q-regs use compile-time parity (no runtime-indexed reg arrays).
// ws byte-image identical to R5 -> xform kernel unchanged.
// Fallbacks: R3 kernel (ws too small), scalar bf16-world kernel.
// =====================================================================

#define DD   300
#define LL   128
#define TOUT 124
// fallback tiling
#define CH   16
#define XR   20
#define NSTG 8
#define BLK  320
// R3-fallback MFMA tiling
#define KS     19
#define SLABP  6080
#define ROWP   20
// ws layout (bytes): G1 19 planes, CV 95 planes, 10,240 B each
#define WS_G1_OFF  0
#define WS_CV_OFF  194560
#define WS_NEEDED  1167360
#define NPH        114

typedef __attribute__((ext_vector_type(8))) _Float16 f16x8;
typedef __attribute__((ext_vector_type(4))) _Float16 f16x4;
typedef __attribute__((ext_vector_type(4))) float f32x4;
typedef __attribute__((ext_vector_type(16))) float f32x16;
typedef unsigned int   u32;
typedef unsigned short u16;
typedef __attribute__((ext_vector_type(4))) u32 u32x4;

__device__ __forceinline__ float b2f(u16 u) {
    union { float f; u32 i; } x; x.i = ((u32)u) << 16; return x.f;
}
__device__ __forceinline__ u16 f2bu(float f) {
    union { float f; u32 i; } x; x.f = f;
    u32 r = x.i + 0x7FFFu + ((x.i >> 16) & 1u);
    return (u16)(r >> 16);
}
__device__ __forceinline__ float ld(const void* p, size_t idx, int is32) {
    return is32 ? ((const float*)p)[idx] : b2f(((const u16*)p)[idx]);
}
__device__ __forceinline__ int sniff_is32(const void* W1) {
    int cnt = 0;
    const u32* w1raw = (const u32*)W1;
    for (int i = 0; i < 64; ++i) {
        u32 e = (w1raw[i] >> 7) & 0xFFu;
        cnt += (e >= 100u && e <= 126u) ? 1 : 0;
    }
    return (cnt < 32) ? 1 : 0;
}

__device__ __forceinline__ void barrier_lgkm() {
    asm volatile("s_waitcnt lgkmcnt(0)" ::: "memory");
    __builtin_amdgcn_s_barrier();
}

// unit u in [0,1216): o = u%304, kq = u/304   (R3 fallback)
__device__ __forceinline__ void unit_decomp(int u, int& o, int& kq) {
    kq = (u >= 912) ? 3 : (u >= 608) ? 2 : (u >= 304) ? 1 : 0;
    o  = u - 304 * kq;
}
__device__ __forceinline__ void g1_load(const float* W1f, int kk, int o, int kq, float r[4]) {
    const int kbase = kk * 16 + kq * 4;
    #pragma unroll
    for (int j = 0; j < 4; ++j) {
        const int k = kbase + j;
        r[j] = (k < DD && o < DD) ? W1f[(size_t)k * DD + o] : 0.f;
    }
}
__device__ __forceinline__ void g1_write(_Float16* Ws, int o, int kq, const float r[4]) {
    f16x4 v;
    #pragma unroll
    for (int j = 0; j < 4; ++j) v[j] = (_Float16)r[j];
    *(f16x4*)&Ws[o * ROWP + (kq << 2)] = v;
}
__device__ __forceinline__ void cv_load(const float* CWf, int kk, int o, int kq, float r[20]) {
    const int kbase = kk * 16 + kq * 4;
    const bool ok = (o < DD) && (kbase < DD);
    const float4* src = (const float4*)(CWf + (size_t)o * 1500 + kk * 80 + kq * 20);
    #pragma unroll
    for (int i = 0; i < 5; ++i) {
        float4 t = ok ? src[i] : float4{0.f, 0.f, 0.f, 0.f};
        r[4*i] = t.x; r[4*i+1] = t.y; r[4*i+2] = t.z; r[4*i+3] = t.w;
    }
}
__device__ __forceinline__ void cv_write(_Float16* Ws, int o, int kq, const float r[20]) {
    #pragma unroll
    for (int s = 0; s < 5; ++s) {
        f16x4 v;
        #pragma unroll
        for (int j = 0; j < 4; ++j) v[j] = (_Float16)r[j * 5 + s];
        *(f16x4*)&Ws[s * SLABP + o * ROWP + (kq << 2)] = v;
    }
}

// ============ transform: weights -> fp16 K-major plane images ============
// grid (19, 6): x = kk; y==0 -> W1 plane [2][320][8]; y=1..5 -> conv s-plane
__global__ void CNNEncoder_36258113912977_xform(
    const void* W1, const void* conv_w, void* ws)
{
    if (!sniff_is32(W1)) return;     // bf16 world: never touch ws
    const int kk = blockIdx.x, part = blockIdx.y, tid = threadIdx.x;

    if (part == 0) {
        const float* W1f = (const float*)W1;
        f16x8* dst = (f16x8*)((char*)ws + WS_G1_OFF) + (size_t)kk * 640;
        for (int g = tid; g < 640; g += 512) {
            const int kc = (g >= 320) ? 1 : 0;
            const int nn = g - kc * 320;
            f16x8 v;
            #pragma unroll
            for (int e = 0; e < 8; ++e) {
                const int k = kk * 16 + kc * 8 + e;
                v[e] = (_Float16)((k < DD && nn < DD) ? W1f[(size_t)k * DD + nn] : 0.f);
            }
            dst[g] = v;
        }
    } else {
        const int s = part - 1;
        const float* CWf = (const float*)conv_w;
        f16x8* dst = (f16x8*)((char*)ws + WS_CV_OFF) + (size_t)kk * 3200 + (size_t)s * 640;
        for (int g = tid; g < 640; g += 512) {
            const int kc = (g >= 320) ? 1 : 0;
            const int nn = g - kc * 320;
            f16x8 v;
            #pragma unroll
            for (int e = 0; e < 8; ++e) {
                const int k = kk * 16 + kc * 8 + e;
                v[e] = (_Float16)((k < DD && nn < DD)
                        ? CWf[(size_t)nn * 1500 + (size_t)k * 5 + s] : 0.f);
            }
            dst[g] = v;
        }
    }
}

// ====== fast path (ws): 32x32x16 f16 MFMA, 6-plane ring pipeline ======
// phase p: write plane p+5 from q, load plane p+7 into q, compute plane p
#define STAGE_PH(P, Q, QX) do {                                             \
    const int wr_ = (P) + 5;                                                \
    if (wr_ < NPH) {                                                        \
        _Float16* d_ = &ring[(wr_ % 6) * 5120];                             \
        *(u32x4*)&d_[tid * 8] = Q;                                          \
        if (tid < 128) *(u32x4*)&d_[(512 + tid) * 8] = QX;                  \
    }                                                                       \
    const int lp_ = (P) + 7;                                                \
    if (lp_ < NPH) {                                                        \
        const u32x4* s_ = (const u32x4*)wsAll + (size_t)lp_ * 640;          \
        Q = s_[tid];                                                        \
        if (tid < 128) QX = s_[512 + tid];                                  \
    }                                                                       \
} while (0)

#define PH_BODY(P, SROW, KKC, Q, QX) do {                                   \
    STAGE_PH((P), Q, QX);                                                   \
    const int phys_ = (P) % 6;                                              \
    const int c_ = 2 * (KKC) + lh;                                          \
    const int row_ = mrow0 + l31 + (SROW);                                  \
    const f16x8 a_ = *(const f16x8*)&XB[row_ * 320 + ((c_ ^ (row_ & 7)) << 3)]; \
    __builtin_amdgcn_s_setprio(1);                                          \
    _Pragma("unroll")                                                       \
    for (int nt_ = 0; nt_ < 5; ++nt_) {                                     \
        const int nn_ = nbase + nt_ * 32 + l31;                             \
        const f16x8 b_ = *(const f16x8*)&ring[phys_ * 5120 + lh * 2560 + nn_ * 8]; \
        acc[nt_] = __builtin_amdgcn_mfma_f32_32x32x16_f16(a_, b_, acc[nt_], 0, 0, 0); \
    }                                                                       \
    __builtin_amdgcn_s_setprio(0);                                          \
    barrier_lgkm();                                                         \
} while (0)

#define PH_G1(KK, Q, QX)    PH_BODY((KK), 0, (KK), Q, QX)
#define PH_CV(KK, S, Q, QX) PH_BODY(19 + (KK) * 5 + (S), (S), (KK), Q, QX)

__global__ __launch_bounds__(512, 2) void CNNEncoder_36258113912977_kernel(
    const int* __restrict__ tok, const void* mention, const void* emb,
    const void* W1, const void* b1, const void* conv_w, const void* conv_b,
    const void* W2, const void* b2, const void* W3, const void* b3,
    void* out, const void* ws)
{
    if (!sniff_is32(W1)) return;          // bf16 world -> scalar fallback

    // 84,480 + 61,440 + 5,120 + 2,400 + 1,200 = 154,640 B (1 block/CU)
    __shared__ __align__(16) _Float16 XB[132 * 320];   // X, then Xh
    __shared__ __align__(16) _Float16 ring[6 * 5120];  // 6-plane ring
    __shared__ float pmax4[4][320];
    __shared__ float cbuf[2 * DD];
    __shared__ float hbuf[DD];

    const int n = blockIdx.x, tid = threadIdx.x;
    const int w   = tid >> 6;
    const int l   = tid & 63;
    const int l31 = l & 31, lh = l >> 5;
    const int wm  = w >> 1;                   // M quarter: rows [32wm,32wm+32)
    const int wn  = w & 1;                    // N half: cols [160wn,160wn+160)
    const int nbase = wn * 160;
    const int mrow0 = wm * 32;
    const int* trow = tok + (size_t)n * LL;
    const void* wsAll = ws;

    u32x4 qE, qO, qEx, qOx;    // staging regs, compile-time parity
    u32x4 pre[5], prex[5];     // prologue planes 0..4

    // ---- issue all prologue loads first (hidden under gather) ----
    #pragma unroll
    for (int pl = 0; pl < 5; ++pl) {
        const u32x4* s_ = (const u32x4*)wsAll + (size_t)pl * 640;
        pre[pl] = s_[tid];
        if (tid < 128) prex[pl] = s_[512 + tid];
    }
    { const u32x4* s_ = (const u32x4*)wsAll + (size_t)5 * 640;
      qE = s_[tid]; if (tid < 128) qEx = s_[512 + tid]; }
    { const u32x4* s_ = (const u32x4*)wsAll + (size_t)6 * 640;
      qO = s_[tid]; if (tid < 128) qOx = s_[512 + tid]; }

    // ---- zero-fill XB (pads rows 128..131, cols 300..319) ----
    for (int i = tid; i < 132 * 160; i += 512) ((u32*)XB)[i] = 0u;
    __syncthreads();

    // ---- gather 128 emb rows, fp32 -> fp16, 16B-chunk XOR swizzle ----
    {
        const int r = tid >> 2, q = tid & 3;
        const float* erow = (const float*)emb + (size_t)trow[r] * DD;
        for (int c = q; c < 38; c += 4) {
            f16x8 v;
            if (c < 37) {
                const float4 f0 = *(const float4*)(erow + 8 * c);
                const float4 f1 = *(const float4*)(erow + 8 * c + 4);
                v[0]=(_Float16)f0.x; v[1]=(_Float16)f0.y;
                v[2]=(_Float16)f0.z; v[3]=(_Float16)f0.w;
                v[4]=(_Float16)f1.x; v[5]=(_Float16)f1.y;
                v[6]=(_Float16)f1.z; v[7]=(_Float16)f1.w;
            } else {
                const float4 f0 = *(const float4*)(erow + 296);
                v[0]=(_Float16)f0.x; v[1]=(_Float16)f0.y;
                v[2]=(_Float16)f0.z; v[3]=(_Float16)f0.w;
                v[4]=(_Float16)0.f; v[5]=(_Float16)0.f;
                v[6]=(_Float16)0.f; v[7]=(_Float16)0.f;
            }
            const int p = c ^ (r & 7);
            *(f16x8*)&XB[r * 320 + (p << 3)] = v;
        }
    }

    // ---- write prologue planes 0..4 into the ring ----
    #pragma unroll
    for (int pl = 0; pl < 5; ++pl) {
        *(u32x4*)&ring[pl * 5120 + tid * 8] = pre[pl];
        if (tid < 128) *(u32x4*)&ring[pl * 5120 + (512 + tid) * 8] = prex[pl];
    }
    __syncthreads();   // XB + planes 0..4 visible

    f32x16 acc[5];
    #pragma unroll
    for (int nt = 0; nt < 5; ++nt)
        #pragma unroll
        for (int j = 0; j < 16; ++j) acc[nt][j] = 0.f;

    // =========== GEMM1: phases 0..18 (Xh = X @ W1) ==========
    for (int kk = 0; kk < 18; kk += 2) {
        PH_G1(kk,     qE, qEx);
        PH_G1(kk + 1, qO, qOx);
    }
    PH_G1(18, qE, qEx);

    // epilogue: +b1, round to fp16, write Xh over XB (own rows only)
    {
        const float* b1f = (const float*)b1;
        #pragma unroll
        for (int nt = 0; nt < 5; ++nt) {
            const int col = nbase + nt * 32 + l31;
            const float bb = (col < DD) ? b1f[col] : 0.f;
            const int cc = col >> 3, c7 = col & 7;
            #pragma unroll
            for (int q = 0; q < 4; ++q) {
                #pragma unroll
                for (int r = 0; r < 4; ++r) {
                    const int row = mrow0 + q * 8 + 4 * lh + r;
                    XB[row * 320 + ((cc ^ (row & 7)) << 3) + c7]
                        = (_Float16)(acc[nt][4 * q + r] + bb);
                }
            }
        }
    }
    __syncthreads();   // Xh visible to all

    // ====== conv: phases 19..113 (Y = sum_s Xh[s:s+.,:] @ Wc_s) ======
    #pragma unroll
    for (int nt = 0; nt < 5; ++nt)
        #pragma unroll
        for (int j = 0; j < 16; ++j) acc[nt][j] = 0.f;

    for (int kk = 0; kk < 18; kk += 2) {
        PH_CV(kk, 0, qO, qOx);  PH_CV(kk, 1, qE, qEx);
        PH_CV(kk, 2, qO, qOx);  PH_CV(kk, 3, qE, qEx);
        PH_CV(kk, 4, qO, qOx);
        PH_CV(kk + 1, 0, qE, qEx);  PH_CV(kk + 1, 1, qO, qOx);
        PH_CV(kk + 1, 2, qE, qEx);  PH_CV(kk + 1, 3, qO, qOx);
        PH_CV(kk + 1, 4, qE, qEx);
    }
    PH_CV(18, 0, qO, qOx);  PH_CV(18, 1, qE, qEx);
    PH_CV(18, 2, qO, qOx);  PH_CV(18, 3, qE, qEx);
    PH_CV(18, 4, qO, qOx);

    // per-wave max over valid t (t = mrow0 + 8q + 4lh + r; exclude 124..127)
    #pragma unroll
    for (int nt = 0; nt < 5; ++nt) {
        float m = -3.0e38f;
        #pragma unroll
        for (int q = 0; q < 4; ++q) {
            if (!(wm == 3 && q == 3)) {
                #pragma unroll
                for (int r = 0; r < 4; ++r) m = fmaxf(m, acc[nt][4 * q + r]);
            } else if (lh == 0) {           // rows 120..123 valid, 124..127 not
                #pragma unroll
                for (int r = 0; r < 4; ++r) m = fmaxf(m, acc[nt][12 + r]);
            }
        }
        m = fmaxf(m, __shfl_xor(m, 32));
        if (lh == 0) pmax4[wm][nbase + nt * 32 + l31] = m;
    }
    __syncthreads();

    // ---- concat = [max + conv_b, mention[n]] ----
    if (tid < DD) {
        float m = fmaxf(fmaxf(pmax4[0][tid], pmax4[1][tid]),
                        fmaxf(pmax4[2][tid], pmax4[3][tid]));
        cbuf[tid]      = m + ((const float*)conv_b)[tid];
        cbuf[DD + tid] = ((const float*)mention)[(size_t)n * DD + tid];
    }
    __syncthreads();

    // ---- h = tanh(concat @ W2 + b2) ----
    if (tid < DD) {
        const float* W2f = (const float*)W2;
        float a0 = 0.f, a1 = 0.f, a2 = 0.f, a3 = 0.f;
        for (int c = 0; c < 2 * DD; c += 4) {
            a0 += cbuf[c]     * W2f[(size_t)c * DD + tid];
            a1 += cbuf[c + 1] * W2f[(size_t)(c + 1) * DD + tid];
            a2 += cbuf[c + 2] * W2f[(size_t)(c + 2) * DD + tid];
            a3 += cbuf[c + 3] * W2f[(size_t)(c + 3) * DD + tid];
        }
        hbuf[tid] = tanhf(((const float*)b2)[tid] + (a0 + a1) + (a2 + a3));
    }
    __syncthreads();

    // ---- out = h @ W3 + b3 (fp32) ----
    if (tid < DD) {
        const float* W3f = (const float*)W3;
        float a0 = 0.f, a1 = 0.f;
        for (int c = 0; c < DD; c += 2) {
            a0 += hbuf[c]     * W3f[(size_t)c * DD + tid];
            a1 += hbuf[c + 1] * W3f[(size_t)(c + 1) * DD + tid];
        }
        ((float*)out)[(size_t)n * DD + tid] = ((const float*)b3)[tid] + a0 + a1;
    }
}

// ============ no-ws fast path: R3 kernel verbatim (proven) ============
__global__ __launch_bounds__(512, 2) void CNNEncoder_36258113912977_nows(
    const int* __restrict__ tok, const void* mention, const void* emb,
    const void* W1, const void* b1, const void* conv_w, const void* conv_b,
    const void* W2, const void* b2, const void* W3, const void* b3,
    void* out)
{
    if (!sniff_is32(W1)) return;

    __shared__ __align__(16) _Float16 XB[132 * 320];
    __shared__ __align__(16) _Float16 Ws[5 * SLABP];
    __shared__ float pmax2[2][304];
    __shared__ float cbuf[2 * DD];
    __shared__ float hbuf[DD];

    const int n = blockIdx.x, tid = threadIdx.x;
    const int w   = tid >> 6;
    const int l   = tid & 63;
    const int l15 = l & 15, lg = l >> 4;
    const int wm  = w >> 2;
    const int wn  = w & 3;
    const int ntw   = (wn < 3) ? 5 : 4;
    const int nbase = wn * 80;
    const int mrow0 = wm * 64;
    const int* trow = tok + (size_t)n * LL;
    const float* W1f = (const float*)W1;
    const float* CWf = (const float*)conv_w;

    int o0, kq0, o1, kq1, o2, kq2;
    unit_decomp(tid, o0, kq0);
    unit_decomp(512 + tid, o1, kq1);
    const bool act2 = (l < 24);
    unit_decomp(1024 + w * 24 + (l < 24 ? l : 0), o2, kq2);

    for (int i = tid; i < 132 * 160; i += 512) ((u32*)XB)[i] = 0u;
    __syncthreads();

    {
        const int r = tid >> 2, q = tid & 3;
        const float* erow = (const float*)emb + (size_t)trow[r] * DD;
        for (int c = q; c < 38; c += 4) {
            f16x8 v;
            if (c < 37) {
                const float4 f0 = *(const float4*)(erow + 8 * c);
                const float4 f1 = *(const float4*)(erow + 8 * c + 4);
                v[0]=(_Float16)f0.x; v[1]=(_Float16)f0.y;
                v[2]=(_Float16)f0.z; v[3]=(_Float16)f0.w;
                v[4]=(_Float16)f1.x; v[5]=(_Float16)f1.y;
                v[6]=(_Float16)f1.z; v[7]=(_Float16)f1.w;
            } else {
                const float4 f0 = *(const float4*)(erow + 296);
                v[0]=(_Float16)f0.x; v[1]=(_Float16)f0.y;
                v[2]=(_Float16)f0.z; v[3]=(_Float16)f0.w;
                v[4]=(_Float16)0.f; v[5]=(_Float16)0.f;
                v[6]=(_Float16)0.f; v[7]=(_Float16)0.f;
            }
            const int p = c ^ (r & 7);
            *(f16x8*)&XB[r * 320 + (p << 3)] = v;
        }
    }

    f32x4 acc[4][5];
    const f32x4 vzero = {0.f, 0.f, 0.f, 0.f};
    #pragma unroll
    for (int mt = 0; mt < 4; ++mt)
        #pragma unroll
        for (int nt = 0; nt < 5; ++nt) acc[mt][nt] = vzero;

    float g1a[4], g1b[4], g1c[4];
    float cfa[20], cfb[20], cfc[20];

    g1_load(W1f, 0, o0, kq0, g1a);
    g1_load(W1f, 0, o1, kq1, g1b);
    if (act2) g1_load(W1f, 0, o2, kq2, g1c);
    __syncthreads();

    for (int kk = 0; kk < KS; ++kk) {
        g1_write(Ws, o0, kq0, g1a);
        g1_write(Ws, o1, kq1, g1b);
        if (act2) g1_write(Ws, o2, kq2, g1c);
        barrier_lgkm();
        if (kk + 1 < KS) {
            g1_load(W1f, kk + 1, o0, kq0, g1a);
            g1_load(W1f, kk + 1, o1, kq1, g1b);
            if (act2) g1_load(W1f, kk + 1, o2, kq2, g1c);
        } else {
            cv_load(CWf, 0, o0, kq0, cfa);
            cv_load(CWf, 0, o1, kq1, cfb);
            if (act2) cv_load(CWf, 0, o2, kq2, cfc);
        }
        {
            f16x4 af[4];
            #pragma unroll
            for (int mt = 0; mt < 4; ++mt) {
                const int row = mrow0 + mt * 16 + l15;
                const int c = (kk << 1) + (lg >> 1);
                af[mt] = *(const f16x4*)&XB[row * 320 + ((c ^ (row & 7)) << 3) + ((lg & 1) << 2)];
            }
            #pragma unroll
            for (int nt = 0; nt < 5; ++nt) {
                if (nt < ntw) {
                    const int nn = nbase + nt * 16 + l15;
                    const f16x4 b = *(const f16x4*)&Ws[nn * ROWP + (lg << 2)];
                    #pragma unroll
                    for (int mt = 0; mt < 4; ++mt)
                        acc[mt][nt] = __builtin_amdgcn_mfma_f32_16x16x16f16(af[mt], b, acc[mt][nt], 0, 0, 0);
                }
            }
        }
        __builtin_amdgcn_s_barrier();
    }

    {
        const float* b1f = (const float*)b1;
        #pragma unroll
        for (int nt = 0; nt < 5; ++nt) {
            if (nt < ntw) {
                const int col = nbase + nt * 16 + l15;
                const float bb = (col < DD) ? b1f[col] : 0.f;
                #pragma unroll
                for (int mt = 0; mt < 4; ++mt) {
                    #pragma unroll
                    for (int j = 0; j < 4; ++j) {
                        const int row = mrow0 + mt * 16 + (lg << 2) + j;
                        XB[row * 320 + (((col >> 3) ^ (row & 7)) << 3) + (col & 7)]
                            = (_Float16)(acc[mt][nt][j] + bb);
                    }
                }
            }
        }
    }

    #pragma unroll
    for (int mt = 0; mt < 4; ++mt)
        #pragma unroll
        for (int nt = 0; nt < 5; ++nt) acc[mt][nt] = vzero;

    for (int kk = 0; kk < KS; ++kk) {
        cv_write(Ws, o0, kq0, cfa);
        cv_write(Ws, o1, kq1, cfb);
        if (act2) cv_write(Ws, o2, kq2, cfc);
        barrier_lgkm();
        if (kk + 1 < KS) {
            cv_load(CWf, kk + 1, o0, kq0, cfa);
            cv_load(CWf, kk + 1, o1, kq1, cfb);
            if (act2) cv_load(CWf, kk + 1, o2, kq2, cfc);
        }
        #pragma unroll
        for (int s = 0; s < 5; ++s) {
            f16x4 af[4];
            #pragma unroll
            for (int mt = 0; mt < 4; ++mt) {
                const int row = mrow0 + mt * 16 + l15 + s;
                const int c = (kk << 1) + (lg >> 1);
                af[mt] = *(const f16x4*)&XB[row * 320 + ((c ^ (row & 7)) << 3) + ((lg & 1) << 2)];
            }
            #pragma unroll
            for (int nt = 0; nt < 5; ++nt) {
                if (nt < ntw) {
                    const int nn = nbase + nt * 16 + l15;
                    const f16x4 b = *(const f16x4*)&Ws[s * SLABP + nn * ROWP + (lg << 2)];
                    #pragma unroll
                    for (int mt = 0; mt < 4; ++mt)
                        acc[mt][nt] = __builtin_amdgcn_mfma_f32_16x16x16f16(af[mt], b, acc[mt][nt], 0, 0, 0);
                }
            }
        }
        __builtin_amdgcn_s_barrier();
    }

    #pragma unroll
    for (int nt = 0; nt < 5; ++nt) {
        if (nt < ntw) {
            float m = -3.0e38f;
            #pragma unroll
            for (int mt = 0; mt < 4; ++mt) {
                #pragma unroll
                for (int j = 0; j < 4; ++j) {
                    const int t = mrow0 + mt * 16 + (lg << 2) + j;
                    if (t < TOUT) m = fmaxf(m, acc[mt][nt][j]);
                }
            }
            m = fmaxf(m, __shfl_xor(m, 16));
            m = fmaxf(m, __shfl_xor(m, 32));
            if (lg == 0) pmax2[wm][nbase + nt * 16 + l15] = m;
        }
    }
    __syncthreads();

    if (tid < DD) {
        const float m = fmaxf(pmax2[0][tid], pmax2[1][tid]);
        cbuf[tid]      = m + ((const float*)conv_b)[tid];
        cbuf[DD + tid] = ((const float*)mention)[(size_t)n * DD + tid];
    }
    __syncthreads();

    if (tid < DD) {
        const float* W2f = (const float*)W2;
        float a0 = 0.f, a1 = 0.f, a2 = 0.f, a3 = 0.f;
        for (int c = 0; c < 2 * DD; c += 4) {
            a0 += cbuf[c]     * W2f[(size_t)c * DD + tid];
            a1 += cbuf[c + 1] * W2f[(size_t)(c + 1) * DD + tid];
            a2 += cbuf[c + 2] * W2f[(size_t)(c + 2) * DD + tid];
            a3 += cbuf[c + 3] * W2f[(size_t)(c + 3) * DD + tid];
        }
        hbuf[tid] = tanhf(((const float*)b2)[tid] + (a0 + a1) + (a2 + a3));
    }
    __syncthreads();

    if (tid < DD) {
        const float* W3f = (const float*)W3;
        float a0 = 0.f, a1 = 0.f;
        for (int c = 0; c < DD; c += 2) {
            a0 += hbuf[c]     * W3f[(size_t)c * DD + tid];
            a1 += hbuf[c + 1] * W3f[(size_t)(c + 1) * DD + tid];
        }
        ((float*)out)[(size_t)n * DD + tid] = ((const float*)b3)[tid] + a0 + a1;
    }
}

// ======== fallback: proven scalar kernel, bf16 world ONLY ========
__global__ void CNNEncoder_36258113912977_fallback(
    const int* tok, const void* mention, const void* emb,
    const void* W1, const void* b1, const void* conv_w, const void* conv_b,
    const void* W2, const void* b2, const void* W3, const void* b3,
    void* out)
{
    __shared__ float g[XR * DD];
    __shared__ float xh[XR * DD];
    __shared__ float concat[2 * DD];
    __shared__ float hbuf[DD];

    const int n = blockIdx.x, tid = threadIdx.x;
    const int* trow = tok + (size_t)n * LL;

    if (sniff_is32(W1)) return;
    const int is32 = 0;

    float mmax = -3.0e38f;

    for (int stage = 0; stage < NSTG; ++stage) {
        const int tbase = stage * CH;
        __syncthreads();

        for (int i = tid; i < XR * DD; i += BLK) {
            int r = i / DD, c = i - (i / DD) * DD;
            int gr = tbase + r; if (gr > 127) gr = 127;
            g[i] = ld(emb, (size_t)trow[gr] * DD + c, is32);
        }
        __syncthreads();

        if (tid < DD) {
            float acc[XR];
            #pragma unroll
            for (int r = 0; r < XR; ++r) acc[r] = 0.f;
            for (int k = 0; k < DD; ++k) {
                float wv = ld(W1, (size_t)k * DD + tid, is32);
                #pragma unroll
                for (int r = 0; r < XR; ++r) acc[r] += g[r * DD + k] * wv;
            }
            float bb = ld(b1, tid, is32);
            #pragma unroll
            for (int r = 0; r < XR; ++r) xh[r * DD + tid] = acc[r] + bb;
        }
        __syncthreads();

        if (tid < DD) {
            float y[CH];
            #pragma unroll
            for (int t = 0; t < CH; ++t) y[t] = 0.f;
            const size_t cwoff = (size_t)tid * (DD * 5);
            for (int k = 0; k < DD; ++k) {
                #pragma unroll
                for (int s = 0; s < 5; ++s) {
                    float wv = ld(conv_w, cwoff + k * 5 + s, is32);
                    #pragma unroll
                    for (int t = 0; t < CH; ++t)
                        y[t] += xh[(t + s) * DD + k] * wv;
                }
            }
            #pragma unroll
            for (int t = 0; t < CH; ++t) {
                int tt = tbase + t;
                if (tt < TOUT) mmax = fmaxf(mmax, y[t]);
            }
        }
    }

    __syncthreads();
    if (tid < DD) {
        concat[tid]      = mmax + ld(conv_b, tid, is32);
        concat[DD + tid] = ld(mention, (size_t)n * DD + tid, is32);
    }
    __syncthreads();

    if (tid < DD) {
        float a = ld(b2, tid, is32);
        for (int c = 0; c < 2 * DD; ++c)
            a += concat[c] * ld(W2, (size_t)c * DD + tid, is32);
        hbuf[tid] = tanhf(a);
    }
    __syncthreads();

    if (tid < DD) {
        float a = ld(b3, tid, is32);
        for (int c = 0; c < DD; ++c)
            a += hbuf[c] * ld(W3, (size_t)c * DD + tid, is32);
        ((u16*)out)[(size_t)n * DD + tid] = f2bu(a);
    }
}

extern "C" void kernel_launch(void* const* d_in, const int* in_sizes, int n_in,
                              void* d_out, int out_size, void* d_ws, size_t ws_size,
                              hipStream_t stream)
{
    if (ws_size >= (size_t)WS_NEEDED && d_ws != nullptr) {
        CNNEncoder_36258113912977_xform<<<dim3(19, 6), 512, 0, stream>>>(
            d_in[3], d_in[5], d_ws);
        CNNEncoder_36258113912977_kernel<<<1024, 512, 0, stream>>>(
            (const int*)d_in[0], d_in[1], d_in[2], d_in[3], d_in[4], d_in[5],
            d_in[6], d_in[7], d_in[8], d_in[9], d_in[10], d_out, d_ws);
    } else {
        CNNEncoder_36258113912977_nows<<<1024, 512, 0, stream>>>(
            (const int*)d_in[0], d_in[1], d_in[2], d_in[3], d_in[4], d_in[5],
            d_in[6], d_in[7], d_in[8], d_in[9], d_in[10], d_out);
    }
    CNNEncoder_36258113912977_fallback<<<1024, BLK, 0, stream>>>(
        (const int*)d_in[0], d_in[1], d_in[2], d_in[3], d_in[4], d_in[5],
        d_in[6], d_in[7], d_in[8], d_in[9], d_in[10], d_out);
}